// Round 5
// baseline (39.269 us; speedup 1.0000x reference)
//
#include <hip/hip_runtime.h>

// ParallelMagLoss: per-row margin-substituted log-softmax CE + one_hot emit.
// Outputs (flat f32): [0]=loss.mean(), [1]=loss_g, [2..]=one_hot (B*C).
//
// R5: phase-split pure streams. K1: flat float4 zero-fill of d_out (clone of
// the 87%-peak fillBuffer pattern). K2: pure-read max-free exp-sum + 256
// scattered one_hot[t]=1 stores. K3: finalize scalars.

#define UA2_INV (1.0f / 12100.0f)   // 1 / (110^2)
#define SEG 8                        // segments per row (power of 2)
#define SEG_SHIFT 3

typedef float v4f __attribute__((ext_vector_type(4)));

__device__ __forceinline__ void fix_target(float4& v, int c, int t4, int kt4,
                                           float ctm_t) {
    if (c == t4) {   // taken for at most one (thread, iteration) per row
        v.x = (kt4 == 0) ? ctm_t : v.x;
        v.y = (kt4 == 1) ? ctm_t : v.y;
        v.z = (kt4 == 2) ? ctm_t : v.z;
        v.w = (kt4 == 3) ? ctm_t : v.w;
    }
}

__device__ __forceinline__ float exp_sum4(const float4& v) {
    return (__expf(v.x) + __expf(v.y)) + (__expf(v.z) + __expf(v.w));
}

// ---- K1: pure write stream -------------------------------------------------
__global__ __launch_bounds__(256) void magloss_fill_kernel(
    v4f* __restrict__ out4,   // d_out as float4 (16B-aligned)
    int n4,                   // number of float4 units
    float* __restrict__ tail, // d_out + 4*n4
    int ntail)                // leftover floats (<4)
{
    const v4f z = {0.f, 0.f, 0.f, 0.f};
    const int stride = gridDim.x * 256;
    for (int i = blockIdx.x * 256 + (int)threadIdx.x; i < n4; i += stride)
        out4[i] = z;
    const int k = blockIdx.x * 256 + (int)threadIdx.x;
    if (k < ntail) tail[k] = 0.f;
}

// ---- K2: pure read stream (+256 scattered dword stores) --------------------
__global__ __launch_bounds__(256) void magloss_exp_kernel(
    const float* __restrict__ ct,     // cos_theta   [B,C]
    const float* __restrict__ ctm,    // cos_theta_m [B,C] (target col only)
    const int*   __restrict__ target, // [B]
    float*       __restrict__ onehot, // d_out + 2   [B,C]
    float*       __restrict__ part,   // ws: [B*SEG] partial exp-sums
    float*       __restrict__ ctmt,   // ws: [B] staged cos_theta_m[target]
    int C)
{
    const int bid = blockIdx.x;
    const int row = bid >> SEG_SHIFT;
    const int seg = bid & (SEG - 1);
    const size_t base = (size_t)row * (size_t)C;
    const int t = target[row];
    const float ctm_t = ctm[base + (size_t)t];

    if (seg == 0 && threadIdx.x == 0) {
        ctmt[row] = ctm_t;
        onehot[base + (size_t)t] = 1.0f;   // the single non-zero of the row
    }

    const int nchunk = C >> 2;
    const int cps = (nchunk + SEG - 1) >> SEG_SHIFT;
    const int c0 = seg * cps;
    const int c1 = min(c0 + cps, nchunk);
    const int t4  = t >> 2;
    const int kt4 = t & 3;

    const float4* __restrict__ ct4 = (const float4*)(ct + base);

    float s0 = 0.f, s1 = 0.f, s2 = 0.f, s3 = 0.f;
    int c = c0 + (int)threadIdx.x;
    for (; c + 768 < c1; c += 1024) {
        float4 a = ct4[c];
        float4 b = ct4[c + 256];
        float4 d = ct4[c + 512];
        float4 e = ct4[c + 768];
        fix_target(a, c,       t4, kt4, ctm_t);
        fix_target(b, c + 256, t4, kt4, ctm_t);
        fix_target(d, c + 512, t4, kt4, ctm_t);
        fix_target(e, c + 768, t4, kt4, ctm_t);
        s0 += exp_sum4(a);
        s1 += exp_sum4(b);
        s2 += exp_sum4(d);
        s3 += exp_sum4(e);
    }
    for (; c < c1; c += 256) {
        float4 a = ct4[c];
        fix_target(a, c, t4, kt4, ctm_t);
        s0 += exp_sum4(a);
    }
    // scalar read tail (C % 4 != 0) — no-op for C=100000
    if (seg == SEG - 1) {
        for (int j = (nchunk << 2) + (int)threadIdx.x; j < C; j += 256) {
            const float v = (j == t) ? ctm_t : ct[base + (size_t)j];
            s1 += __expf(v);
        }
    }

    float s = (s0 + s1) + (s2 + s3);

    #pragma unroll
    for (int off = 32; off; off >>= 1)
        s += __shfl_xor(s, off);

    __shared__ float ss[4];
    const int wave = threadIdx.x >> 6;
    const int lane = threadIdx.x & 63;
    if (lane == 0) ss[wave] = s;
    __syncthreads();

    if (threadIdx.x == 0)
        part[bid] = (ss[0] + ss[1]) + (ss[2] + ss[3]);
}

// ---- K3: scalar finalize ---------------------------------------------------
__global__ __launch_bounds__(256) void magloss_finalize_kernel(
    const float* __restrict__ part,   // ws [B*SEG] partial sums
    const float* __restrict__ ctmt,   // ws [B]
    const float* __restrict__ x_norm, // [B]
    float*       __restrict__ out,    // d_out (out[0], out[1])
    int B)
{
    const int i = threadIdx.x;
    float l = 0.f, g = 0.f;
    for (int r = i; r < B; r += 256) {
        const float* p = part + (r << SEG_SHIFT);
        float S = 0.f;
        #pragma unroll
        for (int sgi = 0; sgi < SEG; ++sgi) S += p[sgi];
        l += __logf(S) - ctmt[r];             // row loss (max-free LSE)
        const float xn = x_norm[r];
        g += xn * UA2_INV + 1.0f / xn;
    }
    #pragma unroll
    for (int off = 32; off; off >>= 1) {
        l += __shfl_xor(l, off);
        g += __shfl_xor(g, off);
    }
    __shared__ float sl[4], sg[4];
    const int wave = i >> 6;
    const int lane = i & 63;
    if (lane == 0) { sl[wave] = l; sg[wave] = g; }
    __syncthreads();
    if (i == 0) {
        float L = 0.f, G = 0.f;
        #pragma unroll
        for (int w = 0; w < 4; ++w) { L += sl[w]; G += sg[w]; }
        out[0] = L / (float)B;
        out[1] = G / (float)B;
    }
}

extern "C" void kernel_launch(void* const* d_in, const int* in_sizes, int n_in,
                              void* d_out, int out_size, void* d_ws, size_t ws_size,
                              hipStream_t stream) {
    const float* ct  = (const float*)d_in[0];
    const float* ctm = (const float*)d_in[1];
    const float* xn  = (const float*)d_in[2];
    const int*   tg  = (const int*)d_in[3];

    const int B = in_sizes[2];
    const int C = in_sizes[0] / B;

    float* out  = (float*)d_out;
    float* part = (float*)d_ws;          // B*SEG floats = 8 KB
    float* ctmt = part + B * SEG;        // B floats

    const int n4    = out_size >> 2;             // float4 units in d_out
    const int ntail = out_size - (n4 << 2);

    magloss_fill_kernel<<<2048, 256, 0, stream>>>((v4f*)out, n4,
                                                  out + ((size_t)n4 << 2), ntail);
    magloss_exp_kernel<<<B * SEG, 256, 0, stream>>>(ct, ctm, tg, out + 2,
                                                    part, ctmt, C);
    magloss_finalize_kernel<<<1, 256, 0, stream>>>(part, ctmt, xn, out, B);
}